// Round 3
// baseline (333.252 us; speedup 1.0000x reference)
//
#include <hip/hip_runtime.h>

typedef float f2 __attribute__((ext_vector_type(2)));

#define WSZ 11
#define PAD 5

__device__ __forceinline__ void gauss_weights(float g[WSZ]) {
    float s = 0.f;
#pragma unroll
    for (int i = 0; i < WSZ; ++i) {
        float x = (float)(i - PAD);
        g[i] = expf(-(x * x) / (2.f * 1.5f * 1.5f));
        s += g[i];
    }
    float inv = 1.f / s;
#pragma unroll
    for (int i = 0; i < WSZ; ++i) g[i] *= inv;
}

__global__ __launch_bounds__(64) void init_accum_kernel(double* accum) {
    if (threadIdx.x < 4) accum[threadIdx.x] = 0.0;
}

// One wave per block. Each block computes a 64-col x RT-row strip of the SSIM
// map, sliding down rows. Horizontal 11-tap from a 74-wide LDS row buffer;
// vertical 11-tap from a register ring (statically indexed via unroll-by-11).
// 2x2 avg-pool fused off the staged raw rows.
__global__ __launch_bounds__(64, 4) void ssim_scale_kernel(
    const float* __restrict__ img1, const float* __restrict__ img2,
    const f2* __restrict__ pair,      // interleaved input for scales>0, else nullptr
    int H, int W, int RT,
    double* __restrict__ accum, int slot,
    f2* __restrict__ pout)            // pooled interleaved output (nullptr on last scale)
{
    __shared__ f2 st[80];             // image cols [ox-5, ox+68] at idx 0..73

    const int lane = threadIdx.x;
    const int ox = blockIdx.x * 64;
    const int r0 = blockIdx.y * RT;
    const int z  = blockIdx.z;
    const size_t base = (size_t)z * H * W;

    float g[WSZ];
    gauss_weights(g);

    const float C1 = 0.01f * 0.01f;
    const float C2 = 0.03f * 0.03f;

    f2 rmu[11], rsq[11];
    float rxx[11];
    f2 psum = {0.f, 0.f};
    float local = 0.f;

    const int NIT = RT + 10;
    const int c0 = ox - PAD + lane;       // this lane's primary staging column
    const int c1 = ox + 59 + lane;        // halo column (lanes 0..9)

#pragma nounroll
    for (int b0 = 0; b0 < NIT; b0 += 11) {
#pragma unroll
        for (int j = 0; j < 11; ++j) {
            const int it = b0 + j;
            if (it < NIT) {
                const int y = r0 - PAD + it;
                // ---- stage one raw row (zero-padded borders) ----
                {
                    f2 v = {0.f, 0.f};
                    if (y >= 0 && y < H && c0 >= 0 && c0 < W) {
                        size_t off = base + (size_t)y * W + c0;
                        v = pair ? pair[off] : (f2){img1[off], img2[off]};
                    }
                    st[lane] = v;
                    if (lane < 10) {
                        f2 v2 = {0.f, 0.f};
                        if (y >= 0 && y < H && c1 < W) {
                            size_t off2 = base + (size_t)y * W + c1;
                            v2 = pair ? pair[off2] : (f2){img1[off2], img2[off2]};
                        }
                        st[64 + lane] = v2;
                    }
                }
                __syncthreads();   // 1-wave block: compiles to a waitcnt, orders write->read

                // ---- horizontal 11-tap ----
                f2 hmu = {0.f, 0.f}, hsq = {0.f, 0.f};
                float hxx = 0.f;
#pragma unroll
                for (int k = 0; k < WSZ; ++k) {
                    f2 p = st[lane + k];
                    f2 q = p * p;
                    hmu += p * g[k];
                    hsq += q * g[k];
                    hxx += p.x * p.y * g[k];
                }
                rmu[j] = hmu; rsq[j] = hsq; rxx[j] = hxx;

                // ---- fused 2x2 avg-pool from the staged raw row ----
                if (pout && lane < 32) {
                    const int yt = it - PAD;          // row within the output tile
                    if (yt >= 0 && yt < RT) {
                        f2 s01 = st[PAD + 2 * lane] + st[PAD + 2 * lane + 1];
                        if ((yt & 1) == 0) {
                            psum = s01;
                        } else {
                            f2 m = (psum + s01) * 0.25f;
                            const int Wo = W >> 1;
                            pout[(size_t)z * (H >> 1) * Wo +
                                 (size_t)((r0 + yt) >> 1) * Wo + (ox >> 1) + lane] = m;
                        }
                    }
                }

                // ---- vertical 11-tap + SSIM (one output row per iteration) ----
                if (it >= 10) {
                    f2 vmu = {0.f, 0.f}, vsq = {0.f, 0.f};
                    float vxx = 0.f;
#pragma unroll
                    for (int k = 0; k < WSZ; ++k) {
                        int s = j + 1 + k; if (s >= 11) s -= 11;   // static after unroll
                        vmu += rmu[s] * g[k];
                        vsq += rsq[s] * g[k];
                        vxx += rxx[s] * g[k];
                    }
                    const float mu1 = vmu.x, mu2 = vmu.y;
                    const float mu11 = mu1 * mu1, mu22 = mu2 * mu2, mu12 = mu1 * mu2;
                    const float sig1 = vsq.x - mu11;
                    const float sig2 = vsq.y - mu22;
                    const float sig12 = vxx - mu12;
                    const float num = (2.f * mu12 + C1) * (2.f * sig12 + C2);
                    const float den = (mu11 + mu22 + C1) * (sig1 + sig2 + C2);
                    local += num * __builtin_amdgcn_rcpf(den);
                }
            }
        }
    }

    // ---- wave-64 reduction, one double atomic per block ----
#pragma unroll
    for (int off = 32; off > 0; off >>= 1) local += __shfl_down(local, off);
    if (lane == 0) atomicAdd(&accum[slot], (double)local);
}

__global__ void finalize_kernel(const double* __restrict__ accum, float* __restrict__ out,
                                double c0, double c1, double c2, double c3)
{
    const double w[4] = {0.0448, 0.2856, 0.3001, 0.2363};
    const double cnt[4] = {c0, c1, c2, c3};
    double loss = 0.0;
#pragma unroll
    for (int s = 0; s < 4; ++s) loss += w[s] * (1.0 - accum[s] / cnt[s]);
    out[0] = (float)loss;
}

extern "C" void kernel_launch(void* const* d_in, const int* in_sizes, int n_in,
                              void* d_out, int out_size, void* d_ws, size_t ws_size,
                              hipStream_t stream) {
    const float* img1 = (const float*)d_in[0];
    const float* img2 = (const float*)d_in[1];
    float* out = (float*)d_out;

    const int H0 = 512, W0 = 512;
    const int NC = in_sizes[0] / (H0 * W0);  // 16*3 = 48

    double* accum = (double*)d_ws;
    f2* p1 = (f2*)((char*)d_ws + 64);                    // NC*256*256 pairs
    f2* p2 = p1 + (size_t)NC * 256 * 256;                // NC*128*128
    f2* p3 = p2 + (size_t)NC * 128 * 128;                // NC*64*64

    init_accum_kernel<<<1, 64, 0, stream>>>(accum);

    {   // Scale 0: 512x512, RT=64 -> 8x8x48 = 3072 waves
        dim3 grid(8, 8, NC);
        ssim_scale_kernel<<<grid, 64, 0, stream>>>(img1, img2, nullptr, 512, 512, 64, accum, 0, p1);
    }
    {   // Scale 1: 256x256, RT=32 -> 4x8x48 = 1536 waves
        dim3 grid(4, 8, NC);
        ssim_scale_kernel<<<grid, 64, 0, stream>>>(nullptr, nullptr, p1, 256, 256, 32, accum, 1, p2);
    }
    {   // Scale 2: 128x128, RT=16 -> 2x8x48 = 768 waves
        dim3 grid(2, 8, NC);
        ssim_scale_kernel<<<grid, 64, 0, stream>>>(nullptr, nullptr, p2, 128, 128, 16, accum, 2, p3);
    }
    {   // Scale 3: 64x64, RT=8 -> 1x8x48 = 384 waves
        dim3 grid(1, 8, NC);
        ssim_scale_kernel<<<grid, 64, 0, stream>>>(nullptr, nullptr, p3, 64, 64, 8, accum, 3, nullptr);
    }

    double c0 = (double)NC * 512.0 * 512.0;
    double c1 = (double)NC * 256.0 * 256.0;
    double c2 = (double)NC * 128.0 * 128.0;
    double c3 = (double)NC * 64.0 * 64.0;
    finalize_kernel<<<1, 1, 0, stream>>>(accum, out, c0, c1, c2, c3);
}

// Round 4
// 276.852 us; speedup vs baseline: 1.2037x; 1.2037x over previous
//
#include <hip/hip_runtime.h>

typedef float f2 __attribute__((ext_vector_type(2)));

#define PAD 5
#define WSZ 11

// Precomputed normalized 11-tap Gaussian (sigma=1.5) — matches fp32 ref far
// within the 1.4e-2 threshold. Hard-coded to keep weights out of VGPRs.
__device__ __forceinline__ float gw(int k) {
    const float G[WSZ] = {
        0.0010283782f, 0.0075987580f, 0.0360007600f, 0.1093607000f,
        0.2130055600f, 0.2660117400f,
        0.2130055600f, 0.1093607000f, 0.0360007600f, 0.0075987580f, 0.0010283782f };
    return G[k];
}

__global__ __launch_bounds__(64) void init_accum_kernel(double* accum) {
    if (threadIdx.x < 4) accum[threadIdx.x] = 0.0;
}

// One wave per block; 64-col x RT-row strip. Depth-2 global prefetch into
// register slots P0/P1 (slot = it&1, static after unroll-by-12). Horizontal
// 11-tap via a 74-wide LDS row (same-wave DS ordering; wavefront fences pin
// the compiler, emit no waitcnt -> prefetch loads stay in flight). Vertical
// 11-tap via a 12-deep register ring (static indices). 2x2 pool fused.
template<int RT, bool PLANAR>
__global__ __launch_bounds__(64, 4) void ssim_scale_kernel(
    const float* __restrict__ img1, const float* __restrict__ img2,
    const f2* __restrict__ pair,
    int H, int W,
    double* __restrict__ accum, int slot,
    f2* __restrict__ pout)
{
    __shared__ f2 st[80];                 // cols ox-5 .. ox+68
    const int lane = threadIdx.x;
    const int ox = blockIdx.x * 64;
    const int r0 = blockIdx.y * RT;
    const int z  = blockIdx.z;
    const size_t base = (size_t)z * H * W;

    constexpr int NIT = RT + 10;
    const float C1 = 1e-4f, C2 = 9e-4f;

    // Per-lane column geometry (iteration-invariant).
    const int c0 = ox - PAD + lane;
    const bool m0 = (c0 >= 0) & (c0 < W);
    const int c0c = min(max(c0, 0), W - 1);
    const int c1 = ox + 59 + lane;                 // halo cols, lanes 0..9
    const bool m1 = (lane < 10) & (c1 < W);
    const int c1c = min(c1, W - 1);

    f2 P0a = {0.f, 0.f}, P0b = {0.f, 0.f};
    f2 P1a = {0.f, 0.f}, P1b = {0.f, 0.f};

    auto issue = [&](int y, f2& A, f2& B) {
        int yc = min(max(y, 0), H - 1);            // clamp; mask at consume
        const size_t roff = base + (size_t)yc * W; // wave-uniform -> SALU
        if (PLANAR) {
            A = (f2){ img1[roff + c0c], img2[roff + c0c] };
            if (lane < 10) B = (f2){ img1[roff + c1c], img2[roff + c1c] };
        } else {
            A = pair[roff + c0c];
            if (lane < 10) B = pair[roff + c1c];
        }
    };

    issue(r0 - PAD + 0, P0a, P0b);
    issue(r0 - PAD + 1, P1a, P1b);

    f2 rmu[12], rsq[12];
    float rxx[12];
    f2 psum = {0.f, 0.f};
    float local = 0.f;
    const f2 zero = {0.f, 0.f};

#pragma clang loop unroll(disable)
    for (int b0 = 0; b0 < NIT; b0 += 12) {
#pragma unroll
        for (int j = 0; j < 12; ++j) {
            const int it = b0 + j;
            if (it < NIT) {
                const int y = r0 - PAD + it;
                const bool yok = (y >= 0) & (y < H);   // wave-uniform

                f2& ca = (j & 1) ? P1a : P0a;          // static slot select
                f2& cb = (j & 1) ? P1b : P0b;
                f2 wa = (yok & m0) ? ca : zero;        // vmcnt wait lands here
                f2 wb = (yok & m1) ? cb : zero;
                issue(y + 2, ca, cb);                  // refill slot: depth-2 prefetch

                __builtin_amdgcn_fence(__ATOMIC_ACQ_REL, "wavefront");
                __builtin_amdgcn_wave_barrier();
                st[lane] = wa;
                if (lane < 10) st[64 + lane] = wb;
                __builtin_amdgcn_fence(__ATOMIC_ACQ_REL, "wavefront");
                __builtin_amdgcn_wave_barrier();

                // Horizontal 11-tap (same-wave DS ordering guarantees RAW).
                f2 hmu = zero, hsq = zero;
                float hxx = 0.f;
#pragma unroll
                for (int k = 0; k < WSZ; ++k) {
                    f2 p = st[lane + k];
                    hmu += p * gw(k);
                    hsq += (p * p) * gw(k);
                    hxx += (p.x * p.y) * gw(k);
                }
                rmu[it % 12] = hmu;                    // it%12 == j: static
                rsq[it % 12] = hsq;
                rxx[it % 12] = hxx;

                // Fused 2x2 avg-pool from the staged raw row.
                if (pout != nullptr) {
                    const int yt = it - PAD;
                    if ((yt >= 0) & (yt < RT) & (lane < 32)) {
                        f2 s01 = st[PAD + 2 * lane] + st[PAD + 2 * lane + 1];
                        if ((yt & 1) == 0) {
                            psum = s01;
                        } else {
                            f2 m = (psum + s01) * 0.25f;
                            const int Wo = W >> 1;
                            pout[(size_t)z * (H >> 1) * Wo +
                                 (size_t)((r0 + yt) >> 1) * Wo + (ox >> 1) + lane] = m;
                        }
                    }
                }

                // Vertical 11-tap + SSIM.
                if (it >= 10) {
                    f2 vmu = zero, vsq = zero;
                    float vxx = 0.f;
#pragma unroll
                    for (int k = 0; k < WSZ; ++k) {
                        const int s = (j + 2 + k) % 12;  // static after unroll
                        vmu += rmu[s] * gw(k);
                        vsq += rsq[s] * gw(k);
                        vxx += rxx[s] * gw(k);
                    }
                    const float mu1 = vmu.x, mu2 = vmu.y;
                    const float mu11 = mu1 * mu1, mu22 = mu2 * mu2, mu12 = mu1 * mu2;
                    const float sig1 = vsq.x - mu11;
                    const float sig2 = vsq.y - mu22;
                    const float sig12 = vxx - mu12;
                    const float num = (2.f * mu12 + C1) * (2.f * sig12 + C2);
                    const float den = (mu11 + mu22 + C1) * (sig1 + sig2 + C2);
                    local += num * __builtin_amdgcn_rcpf(den);
                }
            }
        }
    }

#pragma unroll
    for (int off = 32; off > 0; off >>= 1) local += __shfl_down(local, off);
    if (lane == 0) atomicAdd(&accum[slot], (double)local);
}

__global__ void finalize_kernel(const double* __restrict__ accum, float* __restrict__ out,
                                double c0, double c1, double c2, double c3)
{
    const double w[4] = {0.0448, 0.2856, 0.3001, 0.2363};
    const double cnt[4] = {c0, c1, c2, c3};
    double loss = 0.0;
#pragma unroll
    for (int s = 0; s < 4; ++s) loss += w[s] * (1.0 - accum[s] / cnt[s]);
    out[0] = (float)loss;
}

extern "C" void kernel_launch(void* const* d_in, const int* in_sizes, int n_in,
                              void* d_out, int out_size, void* d_ws, size_t ws_size,
                              hipStream_t stream) {
    const float* img1 = (const float*)d_in[0];
    const float* img2 = (const float*)d_in[1];
    float* out = (float*)d_out;

    const int H0 = 512, W0 = 512;
    const int NC = in_sizes[0] / (H0 * W0);  // 48

    double* accum = (double*)d_ws;
    f2* p1 = (f2*)((char*)d_ws + 64);                 // NC*256*256
    f2* p2 = p1 + (size_t)NC * 256 * 256;             // NC*128*128
    f2* p3 = p2 + (size_t)NC * 128 * 128;             // NC*64*64

    init_accum_kernel<<<1, 64, 0, stream>>>(accum);

    // Scale 0: RT=64 -> 8x8x48 = 3072 waves (12/CU), halo eff 86%
    ssim_scale_kernel<64, true><<<dim3(8, 8, NC), 64, 0, stream>>>(
        img1, img2, nullptr, 512, 512, accum, 0, p1);
    // Scale 1: RT=16 -> 4x16x48 = 3072 waves
    ssim_scale_kernel<16, false><<<dim3(4, 16, NC), 64, 0, stream>>>(
        nullptr, nullptr, p1, 256, 256, accum, 1, p2);
    // Scale 2: RT=8 -> 2x16x48 = 1536 waves
    ssim_scale_kernel<8, false><<<dim3(2, 16, NC), 64, 0, stream>>>(
        nullptr, nullptr, p2, 128, 128, accum, 2, p3);
    // Scale 3: RT=8 -> 1x8x48 = 384 waves
    ssim_scale_kernel<8, false><<<dim3(1, 8, NC), 64, 0, stream>>>(
        nullptr, nullptr, p3, 64, 64, accum, 3, nullptr);

    double c0 = (double)NC * 512.0 * 512.0;
    double c1 = (double)NC * 256.0 * 256.0;
    double c2 = (double)NC * 128.0 * 128.0;
    double c3 = (double)NC * 64.0 * 64.0;
    finalize_kernel<<<1, 1, 0, stream>>>(accum, out, c0, c1, c2, c3);
}